// Round 1
// baseline (353.464 us; speedup 1.0000x reference)
//
#include <hip/hip_runtime.h>
#include <hip/hip_bf16.h>

// Problem constants
#define CIN   128
#define COUT  128
#define DD    36
#define HW    5184
#define DHW   186624          // 36*5184 ; also == L*81 (attn per-channel plane)
#define PATCH 9
#define NPW   576             // HW/9
#define PP    81
#define WHW   36              // hw tile per block (4 patches)
#define NT    3               // n-tiles of 16 (48 >= 36)
#define LDSK  136             // padded k stride (128 + 8) in bf16 elems

typedef __attribute__((ext_vector_type(8))) short bf16x8;
typedef __attribute__((ext_vector_type(4))) float f32x4;

__device__ __forceinline__ short f2bf(float f) {
    // round-to-nearest-even fp32 -> bf16 (inputs are finite; no NaN path needed)
    unsigned u = __builtin_bit_cast(unsigned, f);
    unsigned r = (u + 0x7fffu + ((u >> 16) & 1u)) >> 16;
    return (short)r;
}

__global__ __launch_bounds__(256) void fused_cross_head(
    const float* __restrict__ x,     // [128][36][5184]
    const float* __restrict__ attn,  // [128][2304][81]
    const float* __restrict__ W,     // [128][128]
    const float* __restrict__ bia,   // [128]
    float* __restrict__ out)         // [128][36][5184]
{
    __shared__ __align__(16) short xs[2][48][LDSK];   // transposed bf16 x-tile [n][k]
    __shared__ float inv_lds[COUT][4];                // 1/(nz+1e-5) per (c, patch)

    const int t    = threadIdx.x;
    const int wv   = t >> 6;          // wave 0..3
    const int lane = t & 63;
    const int col  = lane & 15;
    const int quad = lane >> 4;

    const int blk    = blockIdx.x;
    const int pd     = blk / 144;             // 0..3
    const int hwblk  = blk - pd * 144;        // 0..143
    const int hwbase = hwblk * WHW;
    const int lbase  = pd * NPW + hwblk * 4;  // first patch index of this block

    // ---------- Phase 1: nonzero counts -> inv_lds ----------
    // 512 (c,patch) pairs, each owned by one thread (2 per thread).
    for (int pair = t; pair < 512; pair += 256) {
        const int c = pair >> 2, p = pair & 3;
        const float* ap = attn + (size_t)c * DHW + (size_t)(lbase + p) * PP;
        int cnt = 0;
        #pragma unroll 27
        for (int q = 0; q < PP; ++q) cnt += (ap[q] != 0.0f) ? 1 : 0;
        inv_lds[c][p] = 1.0f / ((float)cnt + 1e-5f);
    }

    // ---------- A fragments: W rows for this wave (held across all 9 i's) ----
    // A[m = mbase + mt*16 + col][k = s*32 + quad*8 + j]
    const int wbase = wv * 32;
    bf16x8 afrag[2][4];
    #pragma unroll
    for (int mt = 0; mt < 2; ++mt) {
        const int m = wbase + mt * 16 + col;
        #pragma unroll
        for (int s = 0; s < 4; ++s) {
            const float4* wp4 = (const float4*)(W + m * 128 + s * 32 + quad * 8);
            float4 w0 = wp4[0], w1 = wp4[1];
            bf16x8 f;
            f[0] = f2bf(w0.x); f[1] = f2bf(w0.y); f[2] = f2bf(w0.z); f[3] = f2bf(w0.w);
            f[4] = f2bf(w1.x); f[5] = f2bf(w1.y); f[6] = f2bf(w1.z); f[7] = f2bf(w1.w);
            afrag[mt][s] = f;
        }
    }

    // bias per C/D row this lane will own: row = quad*4 + r within each 16-tile
    float bias[2][4];
    #pragma unroll
    for (int mt = 0; mt < 2; ++mt)
        #pragma unroll
        for (int r = 0; r < 4; ++r)
            bias[mt][r] = bia[wbase + mt * 16 + quad * 4 + r];

    // ---------- Phase 2: per d-row GEMM + fused epilogue ----------
    for (int i = 0; i < 9; ++i) {
        const int buf = i & 1;
        const int d   = pd * PATCH + i;

        // stage x[:, d, hwbase:hwbase+36] -> LDS transposed bf16 [n][k]
        // 128 rows * 9 float4 = 1152 float4 elements
        for (int e = t; e < 1152; e += 256) {
            const int row = e / 9;            // cin
            const int f4  = e - row * 9;      // 0..8
            const float4 v = *(const float4*)(x + (size_t)row * DHW + (size_t)d * HW
                                              + hwbase + f4 * 4);
            const int n0 = f4 * 4;
            xs[buf][n0 + 0][row] = f2bf(v.x);
            xs[buf][n0 + 1][row] = f2bf(v.y);
            xs[buf][n0 + 2][row] = f2bf(v.z);
            xs[buf][n0 + 3][row] = f2bf(v.w);
        }
        __syncthreads();   // also makes phase-1 inv_lds visible on i==0

        f32x4 acc[2][NT];
        #pragma unroll
        for (int mt = 0; mt < 2; ++mt)
            #pragma unroll
            for (int tt = 0; tt < NT; ++tt)
                acc[mt][tt] = (f32x4){0.f, 0.f, 0.f, 0.f};

        #pragma unroll
        for (int s = 0; s < 4; ++s) {
            bf16x8 bfrag[NT];
            #pragma unroll
            for (int tt = 0; tt < NT; ++tt) {
                const short* sp = &xs[buf][tt * 16 + col][s * 32 + quad * 8];
                bfrag[tt] = *(const bf16x8*)sp;   // 16B aligned, conflict-free
            }
            #pragma unroll
            for (int mt = 0; mt < 2; ++mt)
                #pragma unroll
                for (int tt = 0; tt < NT; ++tt)
                    acc[mt][tt] = __builtin_amdgcn_mfma_f32_16x16x32_bf16(
                        afrag[mt][s], bfrag[tt], acc[mt][tt], 0, 0, 0);
        }

        // epilogue: y = acc + bias ; out = lrelu(y*(y + a*inv_nz + 1))
        #pragma unroll
        for (int tt = 0; tt < NT; ++tt) {
            const int n = tt * 16 + col;
            if (n < WHW) {
                const int p  = n / 9;
                const int jj = n - p * 9;
                const int kk = i * 9 + jj;
                #pragma unroll
                for (int mt = 0; mt < 2; ++mt) {
                    #pragma unroll
                    for (int r = 0; r < 4; ++r) {
                        const int c = wbase + mt * 16 + quad * 4 + r;
                        const float y = acc[mt][tt][r] + bias[mt][r];
                        const float a = attn[(size_t)c * DHW + (size_t)(lbase + p) * PP + kk];
                        const float v = y * (y + a * inv_lds[c][p] + 1.0f);
                        out[(size_t)c * DHW + (size_t)d * HW + hwbase + n] =
                            (v >= 0.f) ? v : 0.2f * v;
                    }
                }
            }
        }
        // no trailing barrier: next iter writes the other LDS buffer; the next
        // __syncthreads (after those writes) guarantees this iter's reads done
        // before buf is overwritten two iters later.
    }
}

extern "C" void kernel_launch(void* const* d_in, const int* in_sizes, int n_in,
                              void* d_out, int out_size, void* d_ws, size_t ws_size,
                              hipStream_t stream) {
    const float* x    = (const float*)d_in[0];
    const float* attn = (const float*)d_in[1];
    const float* W    = (const float*)d_in[2];
    const float* b    = (const float*)d_in[3];
    float* out        = (float*)d_out;
    fused_cross_head<<<dim3(576), dim3(256), 0, stream>>>(x, attn, W, b, out);
}

// Round 2
// 314.430 us; speedup vs baseline: 1.1241x; 1.1241x over previous
//
#include <hip/hip_runtime.h>
#include <hip/hip_bf16.h>

// Problem constants
#define CIN   128
#define COUT  128
#define DD    36
#define HW    5184
#define DHW   186624          // 36*5184 ; attn per-channel plane is L*81 = same
#define PATCH 9
#define NPW   576             // patches per d-slab (HW/9)
#define L_TOT 2304            // 4 * 576
#define PP    81
#define LDSK  136             // padded k stride (128 + 8) in bf16 elems

typedef __attribute__((ext_vector_type(8))) short bf16x8;
typedef __attribute__((ext_vector_type(4))) float f32x4;

__device__ __forceinline__ short f2bf(float f) {
    unsigned u = __builtin_bit_cast(unsigned, f);
    unsigned r = (u + 0x7fffu + ((u >> 16) & 1u)) >> 16;
    return (short)r;
}

// ---------------------------------------------------------------------------
// Kernel 1: per-(c,l) nonzero count -> inv table in workspace (1.18 MB)
// ---------------------------------------------------------------------------
__global__ __launch_bounds__(256) void count_nz(
    const float* __restrict__ attn, float* __restrict__ inv)
{
    const int pair = blockIdx.x * 256 + threadIdx.x;   // 0 .. 294911 (c*2304+l)
    const float* ap = attn + (size_t)pair * PP;
    int cnt = 0;
    #pragma unroll
    for (int q = 0; q < PP; ++q) cnt += (ap[q] != 0.0f) ? 1 : 0;
    inv[pair] = 1.0f / ((float)cnt + 1e-5f);
}

// ---------------------------------------------------------------------------
// Kernel 2: fused 1x1x1-conv GEMM + attention epilogue.
// Grid: (d, hwblk) = 36 * 81 blocks; each block: Cout=128 x hw-tile of 64.
// ---------------------------------------------------------------------------
__global__ __launch_bounds__(256) void fused_main(
    const float* __restrict__ x,     // [128][36][5184]
    const float* __restrict__ attn,  // [128][2304][81]
    const float* __restrict__ W,     // [128][128]
    const float* __restrict__ bia,   // [128]
    const float* __restrict__ inv,   // [128][2304]
    float* __restrict__ out)         // [128][36][5184]
{
    __shared__ __align__(16) short xs[64][LDSK];   // transposed bf16 x-tile [n][k]

    const int t    = threadIdx.x;
    const int wv   = t >> 6;
    const int lane = t & 63;
    const int col  = lane & 15;
    const int quad = lane >> 4;

    const int hwblk  = blockIdx.x % 81;       // fastest-varying: write locality
    const int d      = blockIdx.x / 81;       // 0..35
    const int hwbase = hwblk * 64;
    const int lbase  = (d / 9) * NPW;         // l = lbase + hw/9
    const int ii     = d % 9;                 // kernel-row index within patch

    // ---- stage x[:, d, hwbase..+64) -> LDS transposed bf16 [n][k] ----
    // 128 rows * 16 float4, fully coalesced (256 B per row per 16 lanes)
    #pragma unroll
    for (int e = t; e < 2048; e += 256) {
        const int row = e >> 4;               // cin
        const int f4  = e & 15;
        const float4 v = *(const float4*)(x + (size_t)row * DHW + (size_t)d * HW
                                          + hwbase + f4 * 4);
        const int n0 = f4 * 4;
        xs[n0 + 0][row] = f2bf(v.x);
        xs[n0 + 1][row] = f2bf(v.y);
        xs[n0 + 2][row] = f2bf(v.z);
        xs[n0 + 3][row] = f2bf(v.w);
    }

    // ---- A fragments: W rows for this wave (Cout tile = wv*32 .. +32) ----
    const int wbase = wv * 32;
    bf16x8 afrag[2][4];
    #pragma unroll
    for (int mt = 0; mt < 2; ++mt) {
        const int m = wbase + mt * 16 + col;
        #pragma unroll
        for (int s = 0; s < 4; ++s) {
            const float4* wp4 = (const float4*)(W + m * 128 + s * 32 + quad * 8);
            float4 w0 = wp4[0], w1 = wp4[1];
            bf16x8 f;
            f[0] = f2bf(w0.x); f[1] = f2bf(w0.y); f[2] = f2bf(w0.z); f[3] = f2bf(w0.w);
            f[4] = f2bf(w1.x); f[5] = f2bf(w1.y); f[6] = f2bf(w1.z); f[7] = f2bf(w1.w);
            afrag[mt][s] = f;
        }
    }
    float bias[2][4];
    #pragma unroll
    for (int mt = 0; mt < 2; ++mt)
        #pragma unroll
        for (int r = 0; r < 4; ++r)
            bias[mt][r] = bia[wbase + mt * 16 + quad * 4 + r];

    __syncthreads();

    // ---- GEMM: 128(Cout) x 64(n) x 128(K), 16x16x32 MFMA ----
    f32x4 acc[2][4];
    #pragma unroll
    for (int mt = 0; mt < 2; ++mt)
        #pragma unroll
        for (int tt = 0; tt < 4; ++tt)
            acc[mt][tt] = (f32x4){0.f, 0.f, 0.f, 0.f};

    #pragma unroll
    for (int s = 0; s < 4; ++s) {
        bf16x8 bfrag[4];
        #pragma unroll
        for (int tt = 0; tt < 4; ++tt)
            bfrag[tt] = *(const bf16x8*)&xs[tt * 16 + col][s * 32 + quad * 8];
        #pragma unroll
        for (int mt = 0; mt < 2; ++mt)
            #pragma unroll
            for (int tt = 0; tt < 4; ++tt)
                acc[mt][tt] = __builtin_amdgcn_mfma_f32_16x16x32_bf16(
                    afrag[mt][s], bfrag[tt], acc[mt][tt], 0, 0, 0);
    }

    // ---- epilogue: y=acc+bias ; out = lrelu(y*(y + a*inv + 1)) ----
    #pragma unroll
    for (int tt = 0; tt < 4; ++tt) {
        const int n  = tt * 16 + col;
        const int hw = hwbase + n;
        const int p  = hw / 9;
        const int jj = hw - p * 9;
        const int l  = lbase + p;
        const int kk = ii * 9 + jj;
        #pragma unroll
        for (int mt = 0; mt < 2; ++mt) {
            #pragma unroll
            for (int r = 0; r < 4; ++r) {
                const int c = wbase + mt * 16 + quad * 4 + r;
                const float y  = acc[mt][tt][r] + bias[mt][r];
                const float a  = attn[(size_t)c * DHW + (size_t)l * PP + kk];
                const float iv = inv[c * L_TOT + l];
                const float v  = y * (y + a * iv + 1.0f);
                out[(size_t)c * DHW + (size_t)d * HW + hw] =
                    (v >= 0.f) ? v : 0.2f * v;
            }
        }
    }
}

// ---------------------------------------------------------------------------
// Fallback (round-1 kernel, known-good) in case ws is too small for inv table.
// ---------------------------------------------------------------------------
__global__ __launch_bounds__(256) void fused_cross_head_fallback(
    const float* __restrict__ x, const float* __restrict__ attn,
    const float* __restrict__ W, const float* __restrict__ bia,
    float* __restrict__ out)
{
    __shared__ __align__(16) short xs[2][48][LDSK];
    __shared__ float inv_lds[COUT][4];

    const int t = threadIdx.x, wv = t >> 6, lane = t & 63;
    const int col = lane & 15, quad = lane >> 4;
    const int blk = blockIdx.x;
    const int pd = blk / 144, hwblk = blk - pd * 144;
    const int hwbase = hwblk * 36;
    const int lbase = pd * NPW + hwblk * 4;

    for (int pair = t; pair < 512; pair += 256) {
        const int c = pair >> 2, p = pair & 3;
        const float* ap = attn + (size_t)c * DHW + (size_t)(lbase + p) * PP;
        int cnt = 0;
        #pragma unroll 27
        for (int q = 0; q < PP; ++q) cnt += (ap[q] != 0.0f) ? 1 : 0;
        inv_lds[c][p] = 1.0f / ((float)cnt + 1e-5f);
    }
    const int wbase = wv * 32;
    bf16x8 afrag[2][4];
    #pragma unroll
    for (int mt = 0; mt < 2; ++mt) {
        const int m = wbase + mt * 16 + col;
        #pragma unroll
        for (int s = 0; s < 4; ++s) {
            const float4* wp4 = (const float4*)(W + m * 128 + s * 32 + quad * 8);
            float4 w0 = wp4[0], w1 = wp4[1];
            bf16x8 f;
            f[0] = f2bf(w0.x); f[1] = f2bf(w0.y); f[2] = f2bf(w0.z); f[3] = f2bf(w0.w);
            f[4] = f2bf(w1.x); f[5] = f2bf(w1.y); f[6] = f2bf(w1.z); f[7] = f2bf(w1.w);
            afrag[mt][s] = f;
        }
    }
    float bias[2][4];
    #pragma unroll
    for (int mt = 0; mt < 2; ++mt)
        #pragma unroll
        for (int r = 0; r < 4; ++r)
            bias[mt][r] = bia[wbase + mt * 16 + quad * 4 + r];

    for (int i = 0; i < 9; ++i) {
        const int buf = i & 1;
        const int d = pd * PATCH + i;
        for (int e = t; e < 1152; e += 256) {
            const int row = e / 9, f4 = e - row * 9;
            const float4 v = *(const float4*)(x + (size_t)row * DHW + (size_t)d * HW
                                              + hwbase + f4 * 4);
            const int n0 = f4 * 4;
            xs[buf][n0 + 0][row] = f2bf(v.x);
            xs[buf][n0 + 1][row] = f2bf(v.y);
            xs[buf][n0 + 2][row] = f2bf(v.z);
            xs[buf][n0 + 3][row] = f2bf(v.w);
        }
        __syncthreads();
        f32x4 acc[2][3];
        #pragma unroll
        for (int mt = 0; mt < 2; ++mt)
            #pragma unroll
            for (int tt = 0; tt < 3; ++tt)
                acc[mt][tt] = (f32x4){0.f, 0.f, 0.f, 0.f};
        #pragma unroll
        for (int s = 0; s < 4; ++s) {
            bf16x8 bfrag[3];
            #pragma unroll
            for (int tt = 0; tt < 3; ++tt)
                bfrag[tt] = *(const bf16x8*)&xs[buf][tt * 16 + col][s * 32 + quad * 8];
            #pragma unroll
            for (int mt = 0; mt < 2; ++mt)
                #pragma unroll
                for (int tt = 0; tt < 3; ++tt)
                    acc[mt][tt] = __builtin_amdgcn_mfma_f32_16x16x32_bf16(
                        afrag[mt][s], bfrag[tt], acc[mt][tt], 0, 0, 0);
        }
        #pragma unroll
        for (int tt = 0; tt < 3; ++tt) {
            const int n = tt * 16 + col;
            if (n < 36) {
                const int p = n / 9, jj = n - p * 9, kk = i * 9 + jj;
                #pragma unroll
                for (int mt = 0; mt < 2; ++mt) {
                    #pragma unroll
                    for (int r = 0; r < 4; ++r) {
                        const int c = wbase + mt * 16 + quad * 4 + r;
                        const float y = acc[mt][tt][r] + bias[mt][r];
                        const float a = attn[(size_t)c * DHW + (size_t)(lbase + p) * PP + kk];
                        const float v = y * (y + a * inv_lds[c][p] + 1.0f);
                        out[(size_t)c * DHW + (size_t)d * HW + hwbase + n] =
                            (v >= 0.f) ? v : 0.2f * v;
                    }
                }
            }
        }
    }
}

extern "C" void kernel_launch(void* const* d_in, const int* in_sizes, int n_in,
                              void* d_out, int out_size, void* d_ws, size_t ws_size,
                              hipStream_t stream) {
    const float* x    = (const float*)d_in[0];
    const float* attn = (const float*)d_in[1];
    const float* W    = (const float*)d_in[2];
    const float* b    = (const float*)d_in[3];
    float* out        = (float*)d_out;

    const size_t inv_bytes = (size_t)COUT * L_TOT * sizeof(float);  // 1.18 MB
    if (ws_size >= inv_bytes) {
        float* inv = (float*)d_ws;
        count_nz<<<dim3((COUT * L_TOT) / 256), dim3(256), 0, stream>>>(attn, inv);
        fused_main<<<dim3(36 * 81), dim3(256), 0, stream>>>(x, attn, W, b, inv, out);
    } else {
        fused_cross_head_fallback<<<dim3(576), dim3(256), 0, stream>>>(x, attn, W, b, out);
    }
}